// Round 1
// baseline (281.425 us; speedup 1.0000x reference)
//
#include <hip/hip_runtime.h>
#include <hip/hip_bf16.h>

// BatchedNeRFMLP: B=64 batches, N=16384 rays/batch
// params layout per batch (TOTAL=8789 floats):
//   pw [128][63] @ 0      pb [128] @ 8064
//   sw [128]     @ 8192   sb  [1]  @ 8320
//   cw [3][155]  @ 8321   cb  [3]  @ 8786
// outputs: sigma (B*N floats) then rgb (B*N*3 floats), both fp32.

#define NB 64
#define NR 16384
#define NHID 128
#define NTOTAL 8789
#define PI_F 3.14159265358979323846f

__global__ __launch_bounds__(256) void nerf_mlp_kernel(
    const float* __restrict__ pos,
    const float* __restrict__ dir,
    const float* __restrict__ params,
    float* __restrict__ out)
{
    const int b   = blockIdx.x >> 6;                    // 64 blocks per batch
    const int n   = ((blockIdx.x & 63) << 8) + threadIdx.x;
    const long ray = (long)b * NR + n;

    // block-uniform base -> compiler emits scalar (s_load) weight reads
    const float* __restrict__ p = params + b * NTOTAL;

    // ---------------- positional encoding (10 freqs, angle doubling) ----
    float enc[63];
    {
        const float x0 = pos[ray * 3 + 0];
        const float x1 = pos[ray * 3 + 1];
        const float x2 = pos[ray * 3 + 2];
        enc[0] = x0; enc[1] = x1; enc[2] = x2;
        float s0, c0, s1, c1, s2, c2;
        __sincosf(x0 * PI_F, &s0, &c0);
        __sincosf(x1 * PI_F, &s1, &c1);
        __sincosf(x2 * PI_F, &s2, &c2);
        #pragma unroll
        for (int f = 0; f < 10; ++f) {
            enc[3 + f * 6 + 0] = s0;
            enc[3 + f * 6 + 1] = s1;
            enc[3 + f * 6 + 2] = s2;
            enc[3 + f * 6 + 3] = c0;
            enc[3 + f * 6 + 4] = c1;
            enc[3 + f * 6 + 5] = c2;
            float t;
            t = 2.f * s0 * c0; c0 = fmaf(-2.f * s0, s0, 1.f); s0 = t;
            t = 2.f * s1 * c1; c1 = fmaf(-2.f * s1, s1, 1.f); s1 = t;
            t = 2.f * s2 * c2; c2 = fmaf(-2.f * s2, s2, 1.f); s2 = t;
        }
    }

    const float* __restrict__ pw = p;           // [128][63]
    const float* __restrict__ pb = p + 8064;    // [128]
    const float* __restrict__ sw = p + 8192;    // [128]
    const float* __restrict__ cw = p + 8321;    // [3][155]

    float sig = p[8320];        // sb
    float r0  = p[8786];        // cb
    float r1  = p[8787];
    float r2  = p[8788];

    // ---------------- hidden layer fused with both heads ----------------
    #pragma unroll 2
    for (int h = 0; h < NHID; ++h) {
        const float* __restrict__ w = pw + h * 63;
        float acc = pb[h];
        #pragma unroll
        for (int d = 0; d < 63; ++d)
            acc = fmaf(enc[d], w[d], acc);
        acc = fmaxf(acc, 0.0f);                 // relu
        sig = fmaf(acc, sw[h], sig);
        r0  = fmaf(acc, cw[      h], r0);
        r1  = fmaf(acc, cw[155 + h], r1);
        r2  = fmaf(acc, cw[310 + h], r2);
    }

    // ---------------- direction encoding (4 freqs) + rgb tail -----------
    {
        float de[27];
        const float x0 = dir[ray * 3 + 0];
        const float x1 = dir[ray * 3 + 1];
        const float x2 = dir[ray * 3 + 2];
        de[0] = x0; de[1] = x1; de[2] = x2;
        float s0, c0, s1, c1, s2, c2;
        __sincosf(x0 * PI_F, &s0, &c0);
        __sincosf(x1 * PI_F, &s1, &c1);
        __sincosf(x2 * PI_F, &s2, &c2);
        #pragma unroll
        for (int f = 0; f < 4; ++f) {
            de[3 + f * 6 + 0] = s0;
            de[3 + f * 6 + 1] = s1;
            de[3 + f * 6 + 2] = s2;
            de[3 + f * 6 + 3] = c0;
            de[3 + f * 6 + 4] = c1;
            de[3 + f * 6 + 5] = c2;
            float t;
            t = 2.f * s0 * c0; c0 = fmaf(-2.f * s0, s0, 1.f); s0 = t;
            t = 2.f * s1 * c1; c1 = fmaf(-2.f * s1, s1, 1.f); s1 = t;
            t = 2.f * s2 * c2; c2 = fmaf(-2.f * s2, s2, 1.f); s2 = t;
        }
        #pragma unroll
        for (int j = 0; j < 27; ++j) {
            r0 = fmaf(de[j], cw[128 + j],       r0);
            r1 = fmaf(de[j], cw[155 + 128 + j], r1);
            r2 = fmaf(de[j], cw[310 + 128 + j], r2);
        }
    }

    // sigmoid on rgb only (sigma is raw linear output)
    r0 = 1.0f / (1.0f + __expf(-r0));
    r1 = 1.0f / (1.0f + __expf(-r1));
    r2 = 1.0f / (1.0f + __expf(-r2));

    out[ray] = sig;
    float* __restrict__ rgb = out + (long)NB * NR;
    rgb[ray * 3 + 0] = r0;
    rgb[ray * 3 + 1] = r1;
    rgb[ray * 3 + 2] = r2;
}

extern "C" void kernel_launch(void* const* d_in, const int* in_sizes, int n_in,
                              void* d_out, int out_size, void* d_ws, size_t ws_size,
                              hipStream_t stream) {
    const float* pos    = (const float*)d_in[0];
    const float* dirs   = (const float*)d_in[1];
    const float* params = (const float*)d_in[2];
    float* out = (float*)d_out;

    dim3 grid(NB * (NR / 256));   // 4096 blocks, 64 per batch
    dim3 block(256);
    nerf_mlp_kernel<<<grid, block, 0, stream>>>(pos, dirs, params, out);
}

// Round 3
// 66.457 us; speedup vs baseline: 4.2347x; 4.2347x over previous
//
#include <hip/hip_runtime.h>
#include <hip/hip_bf16.h>

// BatchedNeRFMLP: B=64, N=16384, HID=128, POS_IN=63 (pad to 64), DIR_IN=27
// params per batch (TOTAL=8789 fp32):
//   pw [128][63] @0   pb[128]@8064   sw[128]@8192  sb@8320
//   cw [3][155] @8321 cb[3]@8786
// out: sigma (B*N) then rgb (B*N*3), fp32.
//
// Layer-1 via mfma_f32_32x32x16_bf16 with D[h][ray] orientation:
//   A = PW (row=h=lane&31 + 32*mt, k=d=8*(lane>>5)+i+16*ks)  [register-stationary]
//   B = ENC^T from LDS (col=ray=lane&31, same k pattern)     [XOR-swizzled LDS]
//   D: col=lane&31=ray, row(h) = (reg&3)+8*(reg>>2)+4*(lane>>5)  [m74/m101]
// Bias trick: K padded 63->64 with enc[63]=1.0 and A[k=63]=pb[h], so the
// hidden bias is folded into the MFMA (round-2 bug: pb was dropped).
// Heads (sigma,r,g,b; K=128) as a second MFMA: W2 rows duplicated every 4 so
// both lane halves get results; H repacked to B-frags in-register via
// relu -> bf16 pack -> __shfl_xor(,32) half exchange.

#define NB 64
#define NRAY 16384
#define NTOTAL 8789
#define PI_F 3.14159265358979323846f

typedef short bf16x8 __attribute__((ext_vector_type(8)));
typedef float f32x16 __attribute__((ext_vector_type(16)));

union U8 { unsigned u[4]; bf16x8 v; };

__device__ __forceinline__ unsigned bfbits(float x) {
    __hip_bfloat16 h = __float2bfloat16(x);
    return (unsigned)*reinterpret_cast<unsigned short*>(&h);
}
__device__ __forceinline__ unsigned pk2(float a, float b) {
    return bfbits(a) | (bfbits(b) << 16);
}

__global__ __launch_bounds__(256, 2) void nerf_mfma_kernel(
    const float* __restrict__ pos,
    const float* __restrict__ dir,
    const float* __restrict__ params,
    float* __restrict__ out)
{
    const int tid  = threadIdx.x;
    const int lane = tid & 63;
    const int wid  = tid >> 6;
    const int hi   = lane >> 5;      // 0 = lo half, 1 = hi half
    const int l31  = lane & 31;

    const int b     = blockIdx.x >> 4;          // 16 blocks per batch
    const int chunk = (blockIdx.x & 15) << 10;  // 1024 rays per block
    const float* __restrict__ p = params + b * NTOTAL;

    __shared__ uint4 encs[2048];                // 256 rows x 128B, swizzled
    char* encb = reinterpret_cast<char*>(encs);

    // ---------------- register-stationary A-frags --------------------------
    // layer-1 weights: aw[mt][ks], h = mt*32 + l31, d = ks*16 + hi*8 + i
    bf16x8 aw[4][4];
    #pragma unroll
    for (int mt = 0; mt < 4; ++mt) {
        const int hrow = mt * 32 + l31;
        const float* wrow = p + hrow * 63;
        #pragma unroll
        for (int ks = 0; ks < 4; ++ks) {
            const int d0 = ks * 16 + hi * 8;
            U8 u;
            #pragma unroll
            for (int j = 0; j < 4; ++j) {
                float e0 = wrow[d0 + 2 * j];
                float e1 = (d0 + 2 * j + 1 == 63) ? p[8064 + hrow]   // pb[h] at k=63
                                                  : wrow[d0 + 2 * j + 1];
                u.u[j] = pk2(e0, e1);
            }
            aw[mt][ks] = u.v;
        }
    }
    // head weights W2 (rows duplicated mod 4): haw[s], k = s*16 + hi*8 + i
    bf16x8 haw[8];
    {
        const int r = l31 & 3;  // 0=sigma(sw), 1..3 = cw rows
        const float* w2 = (r == 0) ? (p + 8192) : (p + 8321 + (r - 1) * 155);
        #pragma unroll
        for (int s = 0; s < 8; ++s) {
            const int k0 = s * 16 + hi * 8;
            U8 u;
            #pragma unroll
            for (int j = 0; j < 4; ++j)
                u.u[j] = pk2(w2[k0 + 2 * j], w2[k0 + 2 * j + 1]);
            haw[s] = u.v;
        }
    }

    const int rayBlock = b * NRAY + chunk;
    float* __restrict__ rgbout = out + (long)NB * NRAY;

    #pragma unroll 1
    for (int it = 0; it < 4; ++it) {
        const int ray = rayBlock + it * 256 + tid;

        // ---------------- positional encoding (fp32, angle doubling) -------
        float enc[64];
        {
            const float x0 = pos[(long)ray * 3 + 0];
            const float x1 = pos[(long)ray * 3 + 1];
            const float x2 = pos[(long)ray * 3 + 2];
            enc[0] = x0; enc[1] = x1; enc[2] = x2;
            float s0, c0, s1, c1, s2, c2;
            __sincosf(x0 * PI_F, &s0, &c0);
            __sincosf(x1 * PI_F, &s1, &c1);
            __sincosf(x2 * PI_F, &s2, &c2);
            #pragma unroll
            for (int f = 0; f < 10; ++f) {
                enc[3 + f * 6 + 0] = s0;
                enc[3 + f * 6 + 1] = s1;
                enc[3 + f * 6 + 2] = s2;
                enc[3 + f * 6 + 3] = c0;
                enc[3 + f * 6 + 4] = c1;
                enc[3 + f * 6 + 5] = c2;
                float t;
                t = 2.f * s0 * c0; c0 = fmaf(-2.f * s0, s0, 1.f); s0 = t;
                t = 2.f * s1 * c1; c1 = fmaf(-2.f * s1, s1, 1.f); s1 = t;
                t = 2.f * s2 * c2; c2 = fmaf(-2.f * s2, s2, 1.f); s2 = t;
            }
            enc[63] = 1.0f;   // K padding column multiplies pb in A -> bias add
        }

        __syncthreads();     // previous iteration's LDS reads complete
        {
            const int swz = (tid & 7) << 4;
            #pragma unroll
            for (int c = 0; c < 8; ++c) {
                uint4 v;
                v.x = pk2(enc[8 * c + 0], enc[8 * c + 1]);
                v.y = pk2(enc[8 * c + 2], enc[8 * c + 3]);
                v.z = pk2(enc[8 * c + 4], enc[8 * c + 5]);
                v.w = pk2(enc[8 * c + 6], enc[8 * c + 7]);
                *reinterpret_cast<uint4*>(encb + tid * 128 + ((c * 16) ^ swz)) = v;
            }
        }
        __syncthreads();

        // ---------------- layer-1 MFMA + head MFMA, per ray n-tile ---------
        float hres[2][4];
        #pragma unroll
        for (int nt = 0; nt < 2; ++nt) {
            f32x16 acc[4];
            #pragma unroll
            for (int mt = 0; mt < 4; ++mt)
                #pragma unroll
                for (int i = 0; i < 16; ++i) acc[mt][i] = 0.f;

            const int row = wid * 64 + nt * 32 + l31;   // LDS row = ray in block-chunk
            const int swz = (row & 7) << 4;
            #pragma unroll
            for (int ks = 0; ks < 4; ++ks) {
                const int kb = ks * 32 + hi * 16;
                bf16x8 be = *reinterpret_cast<const bf16x8*>(encb + row * 128 + (kb ^ swz));
                #pragma unroll
                for (int mt = 0; mt < 4; ++mt)
                    acc[mt] = __builtin_amdgcn_mfma_f32_32x32x16_bf16(aw[mt][ks], be, acc[mt], 0, 0, 0);
            }

            // relu -> bf16 pack -> half-swap -> head MFMA (K=128 over 8 ksteps)
            f32x16 hacc;
            #pragma unroll
            for (int i = 0; i < 16; ++i) hacc[i] = 0.f;
            #pragma unroll
            for (int s = 0; s < 8; ++s) {
                const int mt = s >> 1, rb = (s & 1) * 8;
                const float r0 = fmaxf(acc[mt][rb + 0], 0.f);
                const float r1 = fmaxf(acc[mt][rb + 1], 0.f);
                const float r2 = fmaxf(acc[mt][rb + 2], 0.f);
                const float r3 = fmaxf(acc[mt][rb + 3], 0.f);
                const float r4 = fmaxf(acc[mt][rb + 4], 0.f);
                const float r5 = fmaxf(acc[mt][rb + 5], 0.f);
                const float r6 = fmaxf(acc[mt][rb + 6], 0.f);
                const float r7 = fmaxf(acc[mt][rb + 7], 0.f);
                const unsigned pA = pk2(r0, r1), pB = pk2(r2, r3);
                const unsigned pC = pk2(r4, r5), pD = pk2(r6, r7);
                const unsigned pAx = (unsigned)__shfl_xor((int)pA, 32);
                const unsigned pBx = (unsigned)__shfl_xor((int)pB, 32);
                const unsigned pCx = (unsigned)__shfl_xor((int)pC, 32);
                const unsigned pDx = (unsigned)__shfl_xor((int)pD, 32);
                U8 u;
                u.u[0] = hi ? pCx : pA;
                u.u[1] = hi ? pDx : pB;
                u.u[2] = hi ? pC  : pAx;
                u.u[3] = hi ? pD  : pBx;
                hacc = __builtin_amdgcn_mfma_f32_32x32x16_bf16(haw[s], u.v, hacc, 0, 0, 0);
            }
            hres[nt][0] = hacc[0]; hres[nt][1] = hacc[1];
            hres[nt][2] = hacc[2]; hres[nt][3] = hacc[3];
        }

        // ---------------- per-ray tail: DE part + bias + sigmoid -----------
        // lane's own ray (= tid) corresponds to nt = hi, col = l31.
        const float hv0 = hi ? hres[1][0] : hres[0][0];
        const float hv1 = hi ? hres[1][1] : hres[0][1];
        const float hv2 = hi ? hres[1][2] : hres[0][2];
        const float hv3 = hi ? hres[1][3] : hres[0][3];

        float de[27];
        {
            const float y0 = dir[(long)ray * 3 + 0];
            const float y1 = dir[(long)ray * 3 + 1];
            const float y2 = dir[(long)ray * 3 + 2];
            de[0] = y0; de[1] = y1; de[2] = y2;
            float s0, c0, s1, c1, s2, c2;
            __sincosf(y0 * PI_F, &s0, &c0);
            __sincosf(y1 * PI_F, &s1, &c1);
            __sincosf(y2 * PI_F, &s2, &c2);
            #pragma unroll
            for (int f = 0; f < 4; ++f) {
                de[3 + f * 6 + 0] = s0;
                de[3 + f * 6 + 1] = s1;
                de[3 + f * 6 + 2] = s2;
                de[3 + f * 6 + 3] = c0;
                de[3 + f * 6 + 4] = c1;
                de[3 + f * 6 + 5] = c2;
                float t;
                t = 2.f * s0 * c0; c0 = fmaf(-2.f * s0, s0, 1.f); s0 = t;
                t = 2.f * s1 * c1; c1 = fmaf(-2.f * s1, s1, 1.f); s1 = t;
                t = 2.f * s2 * c2; c2 = fmaf(-2.f * s2, s2, 1.f); s2 = t;
            }
        }

        float sig = hv0 + p[8320];
        float cr  = hv1 + p[8786];
        float cg  = hv2 + p[8787];
        float cbl = hv3 + p[8788];
        #pragma unroll
        for (int j = 0; j < 27; ++j) {
            cr  = fmaf(de[j], p[8321 + 128 + j],       cr);
            cg  = fmaf(de[j], p[8321 + 155 + 128 + j], cg);
            cbl = fmaf(de[j], p[8321 + 310 + 128 + j], cbl);
        }
        cr  = 1.0f / (1.0f + __expf(-cr));
        cg  = 1.0f / (1.0f + __expf(-cg));
        cbl = 1.0f / (1.0f + __expf(-cbl));

        out[ray] = sig;
        rgbout[(long)ray * 3 + 0] = cr;
        rgbout[(long)ray * 3 + 1] = cg;
        rgbout[(long)ray * 3 + 2] = cbl;
    }
}

extern "C" void kernel_launch(void* const* d_in, const int* in_sizes, int n_in,
                              void* d_out, int out_size, void* d_ws, size_t ws_size,
                              hipStream_t stream) {
    const float* pos    = (const float*)d_in[0];
    const float* dirs   = (const float*)d_in[1];
    const float* params = (const float*)d_in[2];
    float* out = (float*)d_out;

    dim3 grid(1024);   // 16 blocks/batch x 64 batches, 1024 rays each
    dim3 block(256);
    nerf_mfma_kernel<<<grid, block, 0, stream>>>(pos, dirs, params, out);
}

// Round 4
// 53.720 us; speedup vs baseline: 5.2387x; 1.2371x over previous
//
#include <hip/hip_runtime.h>
#include <hip/hip_bf16.h>

// BatchedNeRFMLP: B=64, N=16384, HID=128, POS_IN=63 (+bias col -> K=64), DIR_IN=27
// params per batch (TOTAL=8789 fp32):
//   pw [128][63] @0   pb[128]@8064   sw[128]@8192  sb@8320
//   cw [3][155] @8321 cb[3]@8786
// out: sigma (B*N) then rgb (B*N*3), fp32.
//
// Layer-1: mfma_f32_32x32x16_bf16, D[h][ray] (A=weights reg-stationary, B=ENC^T
// via XOR-swizzled LDS). ENC K-order: [x0,x1,x2,1.0, f0:(s0,s1,s2,c0,c1,c2), ...f9]
// so bias=pb rides k=3 and bf16 word-pairs are aligned. A uses same K-order.
// Head (sigma,r,g,b; K=128): W2 K-order PERMUTED by pi(16s+8hi+i) =
// 32*(s>>1)+16*(s&1)+4hi+(i&3)+8*(i>>2)  == exactly the D-row each lane already
// holds in acc reg rb+i -> B-frag built by relu+pack of own regs, NO shuffles.
// No __syncthreads: each wave writes/reads only its own 64 LDS rows
// (wave-local s_waitcnt lgkmcnt(0) is sufficient; DS ops are in-order per wave).

#define NB 64
#define NRAY 16384
#define NTOTAL 8789
#define PI_F 3.14159265358979323846f

typedef short bf16x8 __attribute__((ext_vector_type(8)));
typedef float f32x16 __attribute__((ext_vector_type(16)));

union U8 { unsigned u[4]; bf16x8 v; };

__device__ __forceinline__ unsigned bfbits(float x) {
    __hip_bfloat16 h = __float2bfloat16(x);
    return (unsigned)*reinterpret_cast<unsigned short*>(&h);
}
__device__ __forceinline__ unsigned pk2(float a, float b) {
    return bfbits(a) | (bfbits(b) << 16);
}

__global__ __launch_bounds__(256, 2) void nerf_mfma_kernel(
    const float* __restrict__ pos,
    const float* __restrict__ dir,
    const float* __restrict__ params,
    float* __restrict__ out)
{
    const int tid  = threadIdx.x;
    const int lane = tid & 63;
    const int wid  = tid >> 6;
    const int hi   = lane >> 5;
    const int l31  = lane & 31;

    const int b     = blockIdx.x >> 4;          // 16 blocks per batch
    const int chunk = (blockIdx.x & 15) << 10;  // 1024 rays per block
    const float* __restrict__ p = params + b * NTOTAL;

    __shared__ uint4 encs[2048];                // 256 rows x 128B, swizzled
    char* encb = reinterpret_cast<char*>(encs);

    // ---------------- register-stationary A-frags --------------------------
    // layer-1: k<3 -> d=k ; k==3 -> pb[h] ; k>=4 -> d=k-1
    bf16x8 aw[4][4];
    #pragma unroll
    for (int mt = 0; mt < 4; ++mt) {
        const int hrow = mt * 32 + l31;
        const float* wrow = p + hrow * 63;
        const float bias = p[8064 + hrow];
        #pragma unroll
        for (int ks = 0; ks < 4; ++ks) {
            U8 u;
            #pragma unroll
            for (int j = 0; j < 4; ++j) {
                const int k0 = ks * 16 + hi * 8 + 2 * j;
                const int k1 = k0 + 1;
                const float e0 = (k0 < 3) ? wrow[k0] : (k0 == 3 ? bias : wrow[k0 - 1]);
                const float e1 = (k1 < 3) ? wrow[k1] : (k1 == 3 ? bias : wrow[k1 - 1]);
                u.u[j] = pk2(e0, e1);
            }
            aw[mt][ks] = u.v;
        }
    }
    // head weights, K permuted by pi (see header comment)
    bf16x8 haw[8];
    {
        const int r = l31 & 3;  // 0=sigma(sw), 1..3 = cw rows
        const float* w2 = (r == 0) ? (p + 8192) : (p + 8321 + (r - 1) * 155);
        #pragma unroll
        for (int s = 0; s < 8; ++s) {
            const int base = 32 * (s >> 1) + 16 * (s & 1) + 4 * hi;
            U8 u;
            #pragma unroll
            for (int j = 0; j < 4; ++j) {
                const int i0 = 2 * j, i1 = 2 * j + 1;
                u.u[j] = pk2(w2[base + (i0 & 3) + 8 * (i0 >> 2)],
                             w2[base + (i1 & 3) + 8 * (i1 >> 2)]);
            }
            haw[s] = u.v;
        }
    }

    // shared zero C-operand (saves ~190 v_mov zero-inits per iteration)
    f32x16 FZ;
    #pragma unroll
    for (int i = 0; i < 16; ++i) FZ[i] = 0.f;

    const float sb  = p[8320];
    const float cb0 = p[8786], cb1 = p[8787], cb2 = p[8788];
    const float* __restrict__ cwr = p + 8321 + 128;        // dir part, head r
    const float* __restrict__ cwg = p + 8321 + 155 + 128;  // head g
    const float* __restrict__ cwb2 = p + 8321 + 310 + 128; // head b

    const int rayBlock = b * NRAY + chunk;
    float* __restrict__ rgbout = out + (long)NB * NRAY;
    const long pbase = (long)(rayBlock + tid) * 3;

    // prefetch iter-0 inputs
    float3 P  = *reinterpret_cast<const float3*>(pos + pbase);
    float3 Dv = *reinterpret_cast<const float3*>(dir + pbase);

    #pragma unroll 1
    for (int it = 0; it < 4; ++it) {
        const int ray = rayBlock + it * 256 + tid;

        // prefetch next iteration's inputs (latency hidden under this iter)
        float3 Pn, Dn;
        if (it < 3) {
            Pn = *reinterpret_cast<const float3*>(pos + pbase + (it + 1) * 768);
            Dn = *reinterpret_cast<const float3*>(dir + pbase + (it + 1) * 768);
        }

        // ---- positional encoding: rolling pack straight into LDS ----------
        {
            asm volatile("s_waitcnt lgkmcnt(0)" ::: "memory");  // WAR vs prev reads
            const int swz = (tid & 7) << 4;
            char* myrow = encb + tid * 128;
            float s0, c0, s1, c1, s2, c2;
            __sincosf(P.x * PI_F, &s0, &c0);
            __sincosf(P.y * PI_F, &s1, &c1);
            __sincosf(P.z * PI_F, &s2, &c2);
            unsigned wb[4];
            wb[0] = pk2(P.x, P.y);
            wb[1] = pk2(P.z, 1.0f);
            #pragma unroll
            for (int f = 0; f < 10; ++f) {
                const int w = 2 + 3 * f;
                wb[(w + 0) & 3] = pk2(s0, s1);
                if (((w + 0) & 3) == 3) {
                    uint4 v; v.x = wb[0]; v.y = wb[1]; v.z = wb[2]; v.w = wb[3];
                    *reinterpret_cast<uint4*>(myrow + ((((w + 0) >> 2) * 16) ^ swz)) = v;
                }
                wb[(w + 1) & 3] = pk2(s2, c0);
                if (((w + 1) & 3) == 3) {
                    uint4 v; v.x = wb[0]; v.y = wb[1]; v.z = wb[2]; v.w = wb[3];
                    *reinterpret_cast<uint4*>(myrow + ((((w + 1) >> 2) * 16) ^ swz)) = v;
                }
                wb[(w + 2) & 3] = pk2(c1, c2);
                if (((w + 2) & 3) == 3) {
                    uint4 v; v.x = wb[0]; v.y = wb[1]; v.z = wb[2]; v.w = wb[3];
                    *reinterpret_cast<uint4*>(myrow + ((((w + 2) >> 2) * 16) ^ swz)) = v;
                }
                if (f < 9) {
                    float t;
                    t = 2.f * s0 * c0; c0 = fmaf(-2.f * s0, s0, 1.f); s0 = t;
                    t = 2.f * s1 * c1; c1 = fmaf(-2.f * s1, s1, 1.f); s1 = t;
                    t = 2.f * s2 * c2; c2 = fmaf(-2.f * s2, s2, 1.f); s2 = t;
                }
            }
            asm volatile("s_waitcnt lgkmcnt(0)" ::: "memory");  // writes visible
        }

        // ---- layer-1 + head MFMA, per 32-ray n-tile (wave-local rows) ------
        float hres[2][4];
        #pragma unroll
        for (int nt = 0; nt < 2; ++nt) {
            const int row = wid * 64 + nt * 32 + l31;
            const int swz = (row & 7) << 4;
            bf16x8 be[4];
            #pragma unroll
            for (int ks = 0; ks < 4; ++ks)
                be[ks] = *reinterpret_cast<const bf16x8*>(
                    encb + row * 128 + (((ks * 32 + hi * 16)) ^ swz));

            f32x16 haccA, haccB;
            #pragma unroll
            for (int mt = 0; mt < 4; ++mt) {
                f32x16 accm = __builtin_amdgcn_mfma_f32_32x32x16_bf16(aw[mt][0], be[0], FZ, 0, 0, 0);
                accm = __builtin_amdgcn_mfma_f32_32x32x16_bf16(aw[mt][1], be[1], accm, 0, 0, 0);
                accm = __builtin_amdgcn_mfma_f32_32x32x16_bf16(aw[mt][2], be[2], accm, 0, 0, 0);
                accm = __builtin_amdgcn_mfma_f32_32x32x16_bf16(aw[mt][3], be[3], accm, 0, 0, 0);

                // relu -> pack own regs (pi-permuted K: no cross-lane exchange)
                #pragma unroll
                for (int t = 0; t < 2; ++t) {
                    const int rb = t * 8;
                    U8 u;
                    #pragma unroll
                    for (int j = 0; j < 4; ++j)
                        u.u[j] = pk2(fmaxf(accm[rb + 2 * j], 0.f),
                                     fmaxf(accm[rb + 2 * j + 1], 0.f));
                    const int s = 2 * mt + t;
                    if (t == 0)
                        haccA = __builtin_amdgcn_mfma_f32_32x32x16_bf16(
                            haw[s], u.v, (mt == 0) ? FZ : haccA, 0, 0, 0);
                    else
                        haccB = __builtin_amdgcn_mfma_f32_32x32x16_bf16(
                            haw[s], u.v, (mt == 0) ? FZ : haccB, 0, 0, 0);
                }
            }
            hres[nt][0] = haccA[0] + haccB[0];
            hres[nt][1] = haccA[1] + haccB[1];
            hres[nt][2] = haccA[2] + haccB[2];
            hres[nt][3] = haccA[3] + haccB[3];
        }

        // ---- per-ray tail: dir-encode folded into head FMAs ---------------
        const float hv0 = hi ? hres[1][0] : hres[0][0];
        const float hv1 = hi ? hres[1][1] : hres[0][1];
        const float hv2 = hi ? hres[1][2] : hres[0][2];
        const float hv3 = hi ? hres[1][3] : hres[0][3];

        float sig = hv0 + sb;
        float cr  = hv1 + cb0;
        float cg  = hv2 + cb1;
        float cbl = hv3 + cb2;

        {
            float s0, c0, s1, c1, s2, c2;
            __sincosf(Dv.x * PI_F, &s0, &c0);
            __sincosf(Dv.y * PI_F, &s1, &c1);
            __sincosf(Dv.z * PI_F, &s2, &c2);
            cr  = fmaf(Dv.x, cwr[0], cr);  cg  = fmaf(Dv.x, cwg[0], cg);  cbl = fmaf(Dv.x, cwb2[0], cbl);
            cr  = fmaf(Dv.y, cwr[1], cr);  cg  = fmaf(Dv.y, cwg[1], cg);  cbl = fmaf(Dv.y, cwb2[1], cbl);
            cr  = fmaf(Dv.z, cwr[2], cr);  cg  = fmaf(Dv.z, cwg[2], cg);  cbl = fmaf(Dv.z, cwb2[2], cbl);
            #pragma unroll
            for (int f = 0; f < 4; ++f) {
                const int j = 3 + 6 * f;
                cr = fmaf(s0, cwr[j+0], cr); cg = fmaf(s0, cwg[j+0], cg); cbl = fmaf(s0, cwb2[j+0], cbl);
                cr = fmaf(s1, cwr[j+1], cr); cg = fmaf(s1, cwg[j+1], cg); cbl = fmaf(s1, cwb2[j+1], cbl);
                cr = fmaf(s2, cwr[j+2], cr); cg = fmaf(s2, cwg[j+2], cg); cbl = fmaf(s2, cwb2[j+2], cbl);
                cr = fmaf(c0, cwr[j+3], cr); cg = fmaf(c0, cwg[j+3], cg); cbl = fmaf(c0, cwb2[j+3], cbl);
                cr = fmaf(c1, cwr[j+4], cr); cg = fmaf(c1, cwg[j+4], cg); cbl = fmaf(c1, cwb2[j+4], cbl);
                cr = fmaf(c2, cwr[j+5], cr); cg = fmaf(c2, cwg[j+5], cg); cbl = fmaf(c2, cwb2[j+5], cbl);
                if (f < 3) {
                    float t;
                    t = 2.f * s0 * c0; c0 = fmaf(-2.f * s0, s0, 1.f); s0 = t;
                    t = 2.f * s1 * c1; c1 = fmaf(-2.f * s1, s1, 1.f); s1 = t;
                    t = 2.f * s2 * c2; c2 = fmaf(-2.f * s2, s2, 1.f); s2 = t;
                }
            }
        }

        cr  = 1.0f / (1.0f + __expf(-cr));
        cg  = 1.0f / (1.0f + __expf(-cg));
        cbl = 1.0f / (1.0f + __expf(-cbl));

        out[ray] = sig;
        float3 rgbv; rgbv.x = cr; rgbv.y = cg; rgbv.z = cbl;
        *reinterpret_cast<float3*>(rgbout + (long)ray * 3) = rgbv;

        P = Pn; Dv = Dn;
    }
}

extern "C" void kernel_launch(void* const* d_in, const int* in_sizes, int n_in,
                              void* d_out, int out_size, void* d_ws, size_t ws_size,
                              hipStream_t stream) {
    const float* pos    = (const float*)d_in[0];
    const float* dirs   = (const float*)d_in[1];
    const float* params = (const float*)d_in[2];
    float* out = (float*)d_out;

    dim3 grid(1024);   // 16 blocks/batch x 64 batches, 1024 rays each
    dim3 block(256);
    nerf_mfma_kernel<<<grid, block, 0, stream>>>(pos, dirs, params, out);
}